// Round 1
// baseline (1046.873 us; speedup 1.0000x reference)
//
#include <hip/hip_runtime.h>

// CIN fused kernel, fp32 baseline.
//   B=2048, F0=39, D=16, H=128 per layer, out [B, 256] fp32.
// Layer 1: h1[b,h,d] = sum_{f,q} x[b,f,d] x[b,q,d] W0[h, f*39+q]
// Layer 2: h2[b,h,d] = sum_{f,q} x[b,f,d] h1[b,q,d] W1[h, f*128+q]
// out[b,h]     = sum_d h1[b,h,d]
// out[b,128+h] = sum_d h2[b,h,d]
//
// One block per b (2048 blocks, 128 threads). x, h1, and the per-f
// outer-product row z[q,d] all live in LDS. Thread tile: 4h x 4d.
// Weights pre-transposed to [P, H] in d_ws for coalesced loads.

#define B_   2048
#define F0_  39
#define D_   16
#define H_   128
#define P0_  (F0_ * F0_)   // 1521
#define P1_  (F0_ * H_)    // 4992

__global__ __launch_bounds__(256) void transpose_w_kernel(const float* __restrict__ w,
                                                          float* __restrict__ wt,
                                                          int P) {
  int i = blockIdx.x * 256 + threadIdx.x;
  if (i < P * H_) {
    int p = i >> 7;
    int h = i & 127;
    wt[i] = w[h * P + p];
  }
}

template <bool WT>
__global__ __launch_bounds__(128) void cin_fused_kernel(const float* __restrict__ x,
                                                        const float* __restrict__ w0,
                                                        const float* __restrict__ w1,
                                                        float* __restrict__ out) {
  __shared__ float4 xs4[F0_ * D_ / 4];   // 156:  x[b]  as [f][d]
  __shared__ float4 h1s4[H_ * D_ / 4];   // 512:  h1    as [q][d]
  __shared__ float4 z4[H_ * D_ / 4];     // 512:  z row as [q][d]

  const int tid = threadIdx.x;
  const int b   = blockIdx.x;
  const int hh  = tid >> 2;   // 0..31  (h-quad index)
  const int dd  = tid & 3;    // 0..3   (d-quad index)
  const int h0  = hh << 2;

  // ---- stage x[b] into LDS ----
  {
    const float4* xg = (const float4*)(x + (size_t)b * (F0_ * D_));
    for (int i = tid; i < F0_ * D_ / 4; i += 128) xs4[i] = xg[i];
  }
  __syncthreads();

  float acc[4][4];
#pragma unroll
  for (int i = 0; i < 4; ++i)
#pragma unroll
    for (int j = 0; j < 4; ++j) acc[i][j] = 0.f;

  // ================= layer 1 =================
  for (int f = 0; f < F0_; ++f) {
    // z[q*16+d] = x[f,d] * x[q,d]   (624 floats, cooperative)
    for (int i = tid; i < F0_ * D_ / 4; i += 128) {
      float4 xv = xs4[(f << 2) + (i & 3)];
      float4 qv = xs4[i];
      z4[i] = make_float4(xv.x * qv.x, xv.y * qv.y, xv.z * qv.z, xv.w * qv.w);
    }
    __syncthreads();
    for (int q = 0; q < F0_; ++q) {
      float4 zv = z4[(q << 2) + dd];
      float4 wv;
      if (WT) {
        wv = ((const float4*)w0)[(f * F0_ + q) * (H_ / 4) + hh];
      } else {
        int p = f * F0_ + q;
        wv.x = w0[(h0 + 0) * P0_ + p];
        wv.y = w0[(h0 + 1) * P0_ + p];
        wv.z = w0[(h0 + 2) * P0_ + p];
        wv.w = w0[(h0 + 3) * P0_ + p];
      }
      const float ww[4] = {wv.x, wv.y, wv.z, wv.w};
      const float zz[4] = {zv.x, zv.y, zv.z, zv.w};
#pragma unroll
      for (int hi = 0; hi < 4; ++hi)
#pragma unroll
        for (int di = 0; di < 4; ++di) acc[hi][di] += ww[hi] * zz[di];
    }
    __syncthreads();   // protect z4 before next f's rebuild
  }

  // ---- store h1 to LDS, emit layer-1 output ----
#pragma unroll
  for (int hi = 0; hi < 4; ++hi)
    h1s4[(h0 + hi) * 4 + dd] = make_float4(acc[hi][0], acc[hi][1], acc[hi][2], acc[hi][3]);
  __syncthreads();
  {
    float4 a0 = h1s4[tid * 4 + 0], a1 = h1s4[tid * 4 + 1];
    float4 a2 = h1s4[tid * 4 + 2], a3 = h1s4[tid * 4 + 3];
    float s = (a0.x + a0.y + a0.z + a0.w) + (a1.x + a1.y + a1.z + a1.w) +
              (a2.x + a2.y + a2.z + a2.w) + (a3.x + a3.y + a3.z + a3.w);
    out[(size_t)b * 256 + tid] = s;
  }

  // ================= layer 2 =================
#pragma unroll
  for (int i = 0; i < 4; ++i)
#pragma unroll
    for (int j = 0; j < 4; ++j) acc[i][j] = 0.f;

  for (int f = 0; f < F0_; ++f) {
    // z[q*16+d] = x[f,d] * h1[q,d]   (2048 floats, cooperative)
    for (int i = tid; i < H_ * D_ / 4; i += 128) {
      float4 xv = xs4[(f << 2) + (i & 3)];
      float4 hv = h1s4[i];
      z4[i] = make_float4(xv.x * hv.x, xv.y * hv.y, xv.z * hv.z, xv.w * hv.w);
    }
    __syncthreads();
    for (int q = 0; q < H_; ++q) {
      float4 zv = z4[(q << 2) + dd];
      float4 wv;
      if (WT) {
        wv = ((const float4*)w1)[(f * H_ + q) * (H_ / 4) + hh];
      } else {
        int p = f * H_ + q;
        wv.x = w1[(h0 + 0) * P1_ + p];
        wv.y = w1[(h0 + 1) * P1_ + p];
        wv.z = w1[(h0 + 2) * P1_ + p];
        wv.w = w1[(h0 + 3) * P1_ + p];
      }
      const float ww[4] = {wv.x, wv.y, wv.z, wv.w};
      const float zz[4] = {zv.x, zv.y, zv.z, zv.w};
#pragma unroll
      for (int hi = 0; hi < 4; ++hi)
#pragma unroll
        for (int di = 0; di < 4; ++di) acc[hi][di] += ww[hi] * zz[di];
    }
    __syncthreads();
  }

  // ---- emit layer-2 output (stage tiles through z4) ----
#pragma unroll
  for (int hi = 0; hi < 4; ++hi)
    z4[(h0 + hi) * 4 + dd] = make_float4(acc[hi][0], acc[hi][1], acc[hi][2], acc[hi][3]);
  __syncthreads();
  {
    float4 a0 = z4[tid * 4 + 0], a1 = z4[tid * 4 + 1];
    float4 a2 = z4[tid * 4 + 2], a3 = z4[tid * 4 + 3];
    float s = (a0.x + a0.y + a0.z + a0.w) + (a1.x + a1.y + a1.z + a1.w) +
              (a2.x + a2.y + a2.z + a2.w) + (a3.x + a3.y + a3.z + a3.w);
    out[(size_t)b * 256 + 128 + tid] = s;
  }
}

extern "C" void kernel_launch(void* const* d_in, const int* in_sizes, int n_in,
                              void* d_out, int out_size, void* d_ws, size_t ws_size,
                              hipStream_t stream) {
  const float* x  = (const float*)d_in[0];   // [2048, 39, 16]
  const float* w0 = (const float*)d_in[1];   // [128, 1521, 1]
  const float* w1 = (const float*)d_in[2];   // [128, 4992, 1]
  float* out = (float*)d_out;                // [2048, 256]

  const size_t need = (size_t)(P0_ + P1_) * H_ * sizeof(float);  // ~3.2 MB
  if (ws_size >= need) {
    float* w0t = (float*)d_ws;                       // [1521, 128]
    float* w1t = w0t + (size_t)P0_ * H_;             // [4992, 128]
    int n0 = P0_ * H_, n1 = P1_ * H_;
    transpose_w_kernel<<<(n0 + 255) / 256, 256, 0, stream>>>(w0, w0t, P0_);
    transpose_w_kernel<<<(n1 + 255) / 256, 256, 0, stream>>>(w1, w1t, P1_);
    cin_fused_kernel<true><<<B_, 128, 0, stream>>>(x, w0t, w1t, out);
  } else {
    // workspace too small: correct (slower) fallback reading W in [H, P] layout
    cin_fused_kernel<false><<<B_, 128, 0, stream>>>(x, w0, w1, out);
  }
}

// Round 2
// 131.685 us; speedup vs baseline: 7.9498x; 7.9498x over previous
//
#include <hip/hip_runtime.h>

// CIN via bf16 MFMA.  B=2048, F0=39, D=16, H=128/layer, out [B,256] fp32.
// Layer L: C[m=h][n=(g,d)] = sum_p W[m,p] * z[p,n],  z[(f,q),(g,d)] = x[g,f,d]*hprev[g,q,d]
// Grid: 512 blocks x 256 thr (G=4 batch/block). MFMA 16x16x32 bf16.
// Waves: (khalf, mgroup) k-split -> W read exactly once per block per chunk.
// K chunks of 128: layer1 = 20 chunks (f-pairs, q padded 39->64), layer2 = 39 chunks (f=c).
// W pre-packed to A-frag order by prep kernel (coalesced dwordx4 per lane).
// B-frags built in registers from LDS hT (bf16, [g][q8][d][8] so reads are b128).
// NO __syncthreads in the K-loops.

#define F0   39
#define D_   16
#define H_   128
#define G_   4
#define NBLK 512            // 2048 / G_
#define NC1  20
#define NC2  39
#define P0_  1521
#define P1_  4992
#define FRAG_ELEMS 512      // 64 lanes * 8

typedef __attribute__((ext_vector_type(8))) short   short8;
typedef __attribute__((ext_vector_type(8))) __bf16  bf16x8;
typedef __attribute__((ext_vector_type(4))) float   floatx4;

__device__ __forceinline__ unsigned short bf16rne(float f) {
  unsigned int u = __float_as_uint(f);
  u += 0x7FFFu + ((u >> 16) & 1u);
  return (unsigned short)(u >> 16);
}

// scale 8 bf16 by fp32 s -> 8 bf16 (round-half-up, cheap)
__device__ __forceinline__ short8 scale8(short8 hv, float s) {
  union { short8 v; unsigned int u[4]; } in, outv;
  in.v = hv;
#pragma unroll
  for (int p = 0; p < 4; ++p) {
    unsigned int up = in.u[p];
    float lo = __uint_as_float(up << 16);
    float hi = __uint_as_float(up & 0xFFFF0000u);
    unsigned int rlo = __float_as_uint(lo * s) + 0x8000u;
    unsigned int rhi = __float_as_uint(hi * s) + 0x8000u;
    outv.u[p] = (rlo >> 16) | (rhi & 0xFFFF0000u);
  }
  return outv.v;
}

__device__ __forceinline__ floatx4 mfma16(short8 a, short8 b, floatx4 c) {
  return __builtin_amdgcn_mfma_f32_16x16x32_bf16(
      __builtin_bit_cast(bf16x8, a), __builtin_bit_cast(bf16x8, b), c, 0, 0, 0);
}

// ---------- prep: pack W0/W1 into MFMA A-frag order, bf16 ----------
// wA[c][s(4)][t(8)][lane(64)][j(8)]: element W[m = t*16+(lane&15)][k-of-chunk]
__global__ __launch_bounds__(256) void pack_w_kernel(const float* __restrict__ w0,
                                                     const float* __restrict__ w1,
                                                     unsigned short* __restrict__ wA1,
                                                     unsigned short* __restrict__ wA2) {
  int idx = blockIdx.x * 256 + threadIdx.x;
  const int n1 = NC1 * 4 * 8 * FRAG_ELEMS;
  const int n2 = NC2 * 4 * 8 * FRAG_ELEMS;
  if (idx < n1) {
    int j = idx & 7, lane = (idx >> 3) & 63, t = (idx >> 9) & 7, s = (idx >> 12) & 3, c = idx >> 14;
    int m = t * 16 + (lane & 15);
    int k = s * 32 + (lane >> 4) * 8 + j;
    int f = 2 * c + (k >> 6), q = k & 63;
    float v = (f < F0 && q < F0) ? w0[m * P0_ + f * F0 + q] : 0.f;
    wA1[idx] = bf16rne(v);
  }
  if (idx < n2) {
    int j = idx & 7, lane = (idx >> 3) & 63, t = (idx >> 9) & 7, s = (idx >> 12) & 3, c = idx >> 14;
    int m = t * 16 + (lane & 15);
    int p = c * 128 + s * 32 + (lane >> 4) * 8 + j;
    wA2[idx] = bf16rne(w1[m * P1_ + p]);
  }
}

// ---------- main fused kernel ----------
__global__ __launch_bounds__(256, 2) void cin_mfma_kernel(const float* __restrict__ x,
                                                          const unsigned short* __restrict__ wA1,
                                                          const unsigned short* __restrict__ wA2,
                                                          float* __restrict__ out) {
  __shared__ __align__(16) float xs[G_][F0][D_];                 // 9984 B, fp32 x
  __shared__ __align__(16) unsigned short hTb[G_ * 16 * D_ * 8]; // 16 KB: [g][q8(16)][d][8]
  __shared__ __align__(16) char uA[H_ * 68 * 4];                 // 34.8 KB: xTb (L1) then S
  unsigned short* xTb = (unsigned short*)uA;                     // 8 KB: [g][q8(8)][d][8]
  float (*S)[68] = (float (*)[68])uA;                            // [128][68] fp32 staging

  const int tid   = threadIdx.x;
  const int lane  = tid & 63;
  const int wv    = tid >> 6;
  const int khalf = wv >> 1;   // k-split half
  const int mg    = wv & 1;    // m-group: tiles mg*4 .. mg*4+3
  const int col   = lane & 15; // n-col within tile == d
  const int quad  = lane >> 4;

  // ---- stage x[b0..b0+3] into LDS (coalesced float4) ----
  {
    const float4* xg = (const float4*)(x + (size_t)blockIdx.x * (G_ * F0 * D_));
    float4* xl = (float4*)xs;
    for (int i = tid; i < G_ * F0 * D_ / 4; i += 256) xl[i] = xg[i];
  }
  __syncthreads();

  // ---- build xTb: [g][q8][d][j] = bf16(x[g][q8*8+j][d]), 0-padded q>=39 ----
  for (int i = tid; i < G_ * 8 * D_; i += 256) {
    int d = i & 15, q8 = (i >> 4) & 7, g = i >> 7;
    union { short8 v; unsigned short e[8]; } pk;
#pragma unroll
    for (int j = 0; j < 8; ++j) {
      int q = q8 * 8 + j;
      pk.e[j] = (q < F0) ? bf16rne(xs[g][q][d]) : (unsigned short)0;
    }
    *(short8*)&xTb[(size_t)i * 8] = pk.v;
  }
  __syncthreads();

  floatx4 acc[4][G_];
  const floatx4 zf4 = {0.f, 0.f, 0.f, 0.f};
#pragma unroll
  for (int t = 0; t < 4; ++t)
#pragma unroll
    for (int g = 0; g < G_; ++g) acc[t][g] = zf4;

  // ================= layer 1 =================
  for (int c = 0; c < NC1; ++c) {
    int f = 2 * c + khalf;
    float sx[G_];
#pragma unroll
    for (int g = 0; g < G_; ++g) sx[g] = (f < F0) ? xs[g][f][col] : 0.f;
#pragma unroll
    for (int ss = 0; ss < 2; ++ss) {
      int s = khalf * 2 + ss;
      short8 a[4];
#pragma unroll
      for (int t = 0; t < 4; ++t)
        a[t] = *(const short8*)(wA1 + (size_t)(((c * 4 + s) * 8) + mg * 4 + t) * FRAG_ELEMS + lane * 8);
      int q8 = ss * 4 + quad;
#pragma unroll
      for (int g = 0; g < G_; ++g) {
        short8 hv = *(const short8*)&xTb[(size_t)((g * 8 + q8) * 16 + col) * 8];
        short8 b = scale8(hv, sx[g]);
#pragma unroll
        for (int t = 0; t < 4; ++t) acc[t][g] = mfma16(a[t], b, acc[t][g]);
      }
    }
  }

  // ---- reduce k-halves through S (aliased over xTb; xTb dead now) ----
  __syncthreads();
  if (khalf == 0) {
#pragma unroll
    for (int t = 0; t < 4; ++t)
#pragma unroll
      for (int g = 0; g < G_; ++g)
#pragma unroll
        for (int r = 0; r < 4; ++r)
          S[(mg * 4 + t) * 16 + quad * 4 + r][g * 16 + col] = acc[t][g][r];
  }
  __syncthreads();
  if (khalf == 1) {
#pragma unroll
    for (int t = 0; t < 4; ++t)
#pragma unroll
      for (int g = 0; g < G_; ++g)
#pragma unroll
        for (int r = 0; r < 4; ++r)
          S[(mg * 4 + t) * 16 + quad * 4 + r][g * 16 + col] += acc[t][g][r];
  }
  __syncthreads();

  // ---- hTb: [g][q8(16)][d][j] = bf16(h1[q8*8+j][g*16+d]) ----
  for (int i = tid; i < G_ * 16 * D_; i += 256) {
    int d = i & 15, q8 = (i >> 4) & 15, g = i >> 8;
    union { short8 v; unsigned short e[8]; } pk;
#pragma unroll
    for (int j = 0; j < 8; ++j) pk.e[j] = bf16rne(S[q8 * 8 + j][g * 16 + d]);
    *(short8*)&hTb[(size_t)i * 8] = pk.v;
  }
  // ---- layer-1 output: out[b][h] = sum_d h1[h][g*16+d] ----
  for (int i = tid; i < G_ * H_; i += 256) {
    int h = i & 127, g = i >> 7;
    float sum = 0.f;
#pragma unroll
    for (int d = 0; d < D_; ++d) sum += S[h][g * 16 + d];
    out[((size_t)blockIdx.x * G_ + g) * 256 + h] = sum;
  }
  __syncthreads();

  // ================= layer 2 =================
#pragma unroll
  for (int t = 0; t < 4; ++t)
#pragma unroll
    for (int g = 0; g < G_; ++g) acc[t][g] = zf4;

  for (int c = 0; c < NC2; ++c) {
    float sx[G_];
#pragma unroll
    for (int g = 0; g < G_; ++g) sx[g] = xs[g][c][col];
#pragma unroll
    for (int ss = 0; ss < 2; ++ss) {
      int s = khalf * 2 + ss;
      short8 a[4];
#pragma unroll
      for (int t = 0; t < 4; ++t)
        a[t] = *(const short8*)(wA2 + (size_t)(((c * 4 + s) * 8) + mg * 4 + t) * FRAG_ELEMS + lane * 8);
      int q8 = s * 4 + quad;
#pragma unroll
      for (int g = 0; g < G_; ++g) {
        short8 hv = *(const short8*)&hTb[(size_t)((g * 16 + q8) * 16 + col) * 8];
        short8 b = scale8(hv, sx[g]);
#pragma unroll
        for (int t = 0; t < 4; ++t) acc[t][g] = mfma16(a[t], b, acc[t][g]);
      }
    }
  }

  // ---- reduce k-halves, emit layer-2 output ----
  __syncthreads();
  if (khalf == 0) {
#pragma unroll
    for (int t = 0; t < 4; ++t)
#pragma unroll
      for (int g = 0; g < G_; ++g)
#pragma unroll
        for (int r = 0; r < 4; ++r)
          S[(mg * 4 + t) * 16 + quad * 4 + r][g * 16 + col] = acc[t][g][r];
  }
  __syncthreads();
  if (khalf == 1) {
#pragma unroll
    for (int t = 0; t < 4; ++t)
#pragma unroll
      for (int g = 0; g < G_; ++g)
#pragma unroll
        for (int r = 0; r < 4; ++r)
          S[(mg * 4 + t) * 16 + quad * 4 + r][g * 16 + col] += acc[t][g][r];
  }
  __syncthreads();
  for (int i = tid; i < G_ * H_; i += 256) {
    int h = i & 127, g = i >> 7;
    float sum = 0.f;
#pragma unroll
    for (int d = 0; d < D_; ++d) sum += S[h][g * 16 + d];
    out[((size_t)blockIdx.x * G_ + g) * 256 + 128 + h] = sum;
  }
}

// ---------- fp32 fallback (known-correct, used only if ws too small) ----------
__global__ __launch_bounds__(128) void cin_fused_fallback(const float* __restrict__ x,
                                                          const float* __restrict__ w0,
                                                          const float* __restrict__ w1,
                                                          float* __restrict__ out) {
  __shared__ float4 xs4[F0 * D_ / 4];
  __shared__ float4 h1s4[H_ * D_ / 4];
  __shared__ float4 z4[H_ * D_ / 4];
  const int tid = threadIdx.x;
  const int b = blockIdx.x;
  const int hh = tid >> 2, dd = tid & 3, h0 = hh << 2;
  {
    const float4* xg = (const float4*)(x + (size_t)b * (F0 * D_));
    for (int i = tid; i < F0 * D_ / 4; i += 128) xs4[i] = xg[i];
  }
  __syncthreads();
  float acc[4][4];
#pragma unroll
  for (int i = 0; i < 4; ++i)
#pragma unroll
    for (int j = 0; j < 4; ++j) acc[i][j] = 0.f;
  for (int f = 0; f < F0; ++f) {
    for (int i = tid; i < F0 * D_ / 4; i += 128) {
      float4 xv = xs4[(f << 2) + (i & 3)], qv = xs4[i];
      z4[i] = make_float4(xv.x * qv.x, xv.y * qv.y, xv.z * qv.z, xv.w * qv.w);
    }
    __syncthreads();
    for (int q = 0; q < F0; ++q) {
      float4 zv = z4[(q << 2) + dd];
      int p = f * F0 + q;
      float ww[4] = {w0[(h0 + 0) * P0_ + p], w0[(h0 + 1) * P0_ + p],
                     w0[(h0 + 2) * P0_ + p], w0[(h0 + 3) * P0_ + p]};
      float zz[4] = {zv.x, zv.y, zv.z, zv.w};
#pragma unroll
      for (int hi = 0; hi < 4; ++hi)
#pragma unroll
        for (int di = 0; di < 4; ++di) acc[hi][di] += ww[hi] * zz[di];
    }
    __syncthreads();
  }
#pragma unroll
  for (int hi = 0; hi < 4; ++hi)
    h1s4[(h0 + hi) * 4 + dd] = make_float4(acc[hi][0], acc[hi][1], acc[hi][2], acc[hi][3]);
  __syncthreads();
  {
    float4 a0 = h1s4[tid * 4 + 0], a1 = h1s4[tid * 4 + 1];
    float4 a2 = h1s4[tid * 4 + 2], a3 = h1s4[tid * 4 + 3];
    out[(size_t)b * 256 + tid] = (a0.x + a0.y + a0.z + a0.w) + (a1.x + a1.y + a1.z + a1.w) +
                                 (a2.x + a2.y + a2.z + a2.w) + (a3.x + a3.y + a3.z + a3.w);
  }
#pragma unroll
  for (int i = 0; i < 4; ++i)
#pragma unroll
    for (int j = 0; j < 4; ++j) acc[i][j] = 0.f;
  for (int f = 0; f < F0; ++f) {
    for (int i = tid; i < H_ * D_ / 4; i += 128) {
      float4 xv = xs4[(f << 2) + (i & 3)], hv = h1s4[i];
      z4[i] = make_float4(xv.x * hv.x, xv.y * hv.y, xv.z * hv.z, xv.w * hv.w);
    }
    __syncthreads();
    for (int q = 0; q < H_; ++q) {
      float4 zv = z4[(q << 2) + dd];
      int p = f * H_ + q;
      float ww[4] = {w1[(h0 + 0) * P1_ + p], w1[(h0 + 1) * P1_ + p],
                     w1[(h0 + 2) * P1_ + p], w1[(h0 + 3) * P1_ + p]};
      float zz[4] = {zv.x, zv.y, zv.z, zv.w};
#pragma unroll
      for (int hi = 0; hi < 4; ++hi)
#pragma unroll
        for (int di = 0; di < 4; ++di) acc[hi][di] += ww[hi] * zz[di];
    }
    __syncthreads();
  }
#pragma unroll
  for (int hi = 0; hi < 4; ++hi)
    z4[(h0 + hi) * 4 + dd] = make_float4(acc[hi][0], acc[hi][1], acc[hi][2], acc[hi][3]);
  __syncthreads();
  {
    float4 a0 = z4[tid * 4 + 0], a1 = z4[tid * 4 + 1];
    float4 a2 = z4[tid * 4 + 2], a3 = z4[tid * 4 + 3];
    out[(size_t)b * 256 + 128 + tid] = (a0.x + a0.y + a0.z + a0.w) + (a1.x + a1.y + a1.z + a1.w) +
                                       (a2.x + a2.y + a2.z + a2.w) + (a3.x + a3.y + a3.z + a3.w);
  }
}

extern "C" void kernel_launch(void* const* d_in, const int* in_sizes, int n_in,
                              void* d_out, int out_size, void* d_ws, size_t ws_size,
                              hipStream_t stream) {
  const float* x  = (const float*)d_in[0];
  const float* w0 = (const float*)d_in[1];
  const float* w1 = (const float*)d_in[2];
  float* out = (float*)d_out;

  const size_t n1 = (size_t)NC1 * 4 * 8 * FRAG_ELEMS;
  const size_t n2 = (size_t)NC2 * 4 * 8 * FRAG_ELEMS;
  const size_t need = (n1 + n2) * sizeof(unsigned short);  // ~1.93 MB
  if (ws_size >= need) {
    unsigned short* wA1 = (unsigned short*)d_ws;
    unsigned short* wA2 = wA1 + n1;
    pack_w_kernel<<<(int)(n2 / 256), 256, 0, stream>>>(w0, w1, wA1, wA2);
    cin_mfma_kernel<<<NBLK, 256, 0, stream>>>(x, wA1, wA2, out);
  } else {
    cin_fused_fallback<<<2048, 128, 0, stream>>>(x, w0, w1, out);
  }
}

// Round 3
// 125.418 us; speedup vs baseline: 8.3471x; 1.0500x over previous
//
#include <hip/hip_runtime.h>

// CIN via bf16 MFMA, scale-free inner loop.
//   C[h,(g,d)] = sum_f x[g,f,d] * T_f[h,(g,d)],  T_f = W_f (GEMM) hprev
// B-frags (x for layer1, h1 for layer2) are f-invariant -> cached in VGPRs.
// Per-f epilogue: acc2 += accf * sx[g]  (v_fmac, ~1 VALU per MFMA).
// Grid 512 x 256 (G=4 batch/block, 2 blocks/CU). Waves split M (2 tiles each):
// no cross-wave reduction, W read exactly once per block.

#define F0   39
#define D_   16
#define H_   128
#define G_   4
#define NBLK 512
#define P0_  1521
#define P1_  4992
#define NF1  (F0 * 2 * 8)   // 624 layer-1 frags
#define NF2  (F0 * 4 * 8)   // 1248 layer-2 frags

typedef __attribute__((ext_vector_type(8))) short   short8;
typedef __attribute__((ext_vector_type(8))) __bf16  bf16x8;
typedef __attribute__((ext_vector_type(4))) float   floatx4;

__device__ __forceinline__ unsigned short bf16rne(float f) {
  unsigned int u = __float_as_uint(f);
  u += 0x7FFFu + ((u >> 16) & 1u);
  return (unsigned short)(u >> 16);
}

__device__ __forceinline__ floatx4 mfma16(short8 a, short8 b, floatx4 c) {
  return __builtin_amdgcn_mfma_f32_16x16x32_bf16(
      __builtin_bit_cast(bf16x8, a), __builtin_bit_cast(bf16x8, b), c, 0, 0, 0);
}

// ---------- pack W into A-frag order (one thread per (frag,lane)) ----------
// wA1 frag = (f*2+s)*8 + t : element A[m=t*16+(lane&15)][k=(lane>>4)*8+j] = W0[m][f*39 + s*32+k], 0-pad q>=39
// wA2 frag = (f*4+s)*8 + t : ... = W1[m][f*128 + s*32+k]
__global__ __launch_bounds__(256) void pack_w_kernel(const float* __restrict__ w0,
                                                     const float* __restrict__ w1,
                                                     short8* __restrict__ wA1,
                                                     short8* __restrict__ wA2) {
  int id = blockIdx.x * 256 + threadIdx.x;
  union { short8 v; unsigned short e[8]; } pk;
  if (id < NF1 * 64) {
    int lane = id & 63, frag = id >> 6;
    int t = frag & 7, s = (frag >> 3) & 1, f = frag >> 4;
    int m = t * 16 + (lane & 15);
    int qb = s * 32 + (lane >> 4) * 8;
#pragma unroll
    for (int j = 0; j < 8; ++j) {
      int q = qb + j;
      float v = (q < F0) ? w0[(size_t)m * P0_ + f * F0 + q] : 0.f;
      pk.e[j] = bf16rne(v);
    }
    wA1[frag * 64 + lane] = pk.v;
  } else if (id < (NF1 + NF2) * 64) {
    int u = id - NF1 * 64;
    int lane = u & 63, frag = u >> 6;
    int t = frag & 7, s = (frag >> 3) & 3, f = frag >> 5;
    int m = t * 16 + (lane & 15);
    int pb = f * 128 + s * 32 + (lane >> 4) * 8;
#pragma unroll
    for (int j = 0; j < 8; ++j) pk.e[j] = bf16rne(w1[(size_t)m * P1_ + pb + j]);
    wA2[frag * 64 + lane] = pk.v;
  }
}

// ---------- main fused kernel ----------
__global__ __launch_bounds__(256, 2) void cin_mfma_kernel(const float* __restrict__ x,
                                                          const short8* __restrict__ wA1,
                                                          const short8* __restrict__ wA2,
                                                          float* __restrict__ out) {
  __shared__ __align__(16) float xs[G_][F0][D_];                  // 9984 B
  __shared__ __align__(16) unsigned short xTb[G_ * 8 * D_ * 8];   // 8 KB  [g][q8(8)][d][8]
  __shared__ __align__(16) unsigned short hTb[G_ * 16 * D_ * 8];  // 16 KB [g][q8(16)][d][8]
  __shared__ __align__(16) float S[H_][G_ * D_ + 4];              // 34.8 KB [128][68]

  const int tid  = threadIdx.x;
  const int lane = tid & 63;
  const int wv   = tid >> 6;     // wave owns m-tiles {wv*2, wv*2+1}
  const int t0   = wv * 2;
  const int col  = lane & 15;    // n-col within tile == d
  const int quad = lane >> 4;
  const int b0   = blockIdx.x * G_;
  const floatx4 zf4 = {0.f, 0.f, 0.f, 0.f};

  // ---- stage x[b0..b0+3] (coalesced float4) ----
  {
    const float4* xg = (const float4*)(x + (size_t)b0 * (F0 * D_));
    float4* xl = (float4*)xs;
    for (int i = tid; i < G_ * F0 * D_ / 4; i += 256) xl[i] = xg[i];
  }
  __syncthreads();

  // ---- xTb[g][q8][d][j] = bf16(x[g][q8*8+j][d]), zero-pad q>=39 ----
  for (int i = tid; i < G_ * 8 * D_; i += 256) {
    int d = i & 15, q8 = (i >> 4) & 7, g = i >> 7;
    union { short8 v; unsigned short e[8]; } pk;
#pragma unroll
    for (int j = 0; j < 8; ++j) {
      int q = q8 * 8 + j;
      pk.e[j] = (q < F0) ? bf16rne(xs[g][q][d]) : (unsigned short)0;
    }
    *(short8*)&xTb[(size_t)i * 8] = pk.v;
  }
  __syncthreads();

  // ---- layer-1 B-frags (f-invariant): bx[s][g] ----
  short8 bx[2][G_];
#pragma unroll
  for (int s = 0; s < 2; ++s)
#pragma unroll
    for (int g = 0; g < G_; ++g)
      bx[s][g] = *(const short8*)&xTb[(size_t)(((g * 8 + s * 4 + quad) * 16) + col) * 8];

  floatx4 acc2[2][G_];
#pragma unroll
  for (int tt = 0; tt < 2; ++tt)
#pragma unroll
    for (int g = 0; g < G_; ++g) acc2[tt][g] = zf4;

  // ================= layer 1: 39 f, K=64 (q padded) =================
  for (int f = 0; f < F0; ++f) {
    short8 a[2][2];
#pragma unroll
    for (int s = 0; s < 2; ++s)
#pragma unroll
      for (int tt = 0; tt < 2; ++tt)
        a[s][tt] = wA1[(size_t)((f * 2 + s) * 8 + t0 + tt) * 64 + lane];
    float sx[G_];
#pragma unroll
    for (int g = 0; g < G_; ++g) sx[g] = xs[g][f][col];
#pragma unroll
    for (int tt = 0; tt < 2; ++tt)
#pragma unroll
      for (int g = 0; g < G_; ++g) {
        floatx4 acf = mfma16(a[0][tt], bx[0][g], zf4);
        acf = mfma16(a[1][tt], bx[1][g], acf);
#pragma unroll
        for (int r = 0; r < 4; ++r) acc2[tt][g][r] += acf[r] * sx[g];
      }
  }

  // ---- epilogue 1: stage h1 fp32 in S ----
#pragma unroll
  for (int tt = 0; tt < 2; ++tt)
#pragma unroll
    for (int g = 0; g < G_; ++g)
#pragma unroll
      for (int r = 0; r < 4; ++r)
        S[(t0 + tt) * 16 + quad * 4 + r][g * 16 + col] = acc2[tt][g][r];
  __syncthreads();

  // hTb[g][q8][d][j] = bf16(h1[q8*8+j][g*16+d])
  for (int i = tid; i < G_ * 16 * D_; i += 256) {
    int d = i & 15, q8 = (i >> 4) & 15, g = i >> 8;
    union { short8 v; unsigned short e[8]; } pk;
#pragma unroll
    for (int j = 0; j < 8; ++j) pk.e[j] = bf16rne(S[q8 * 8 + j][g * 16 + d]);
    *(short8*)&hTb[(size_t)i * 8] = pk.v;
  }
  // out[b0+g][h] = sum_d h1
  for (int i = tid; i < G_ * H_; i += 256) {
    int h = i & 127, g = i >> 7;
    const float4* sp = (const float4*)&S[h][g * 16];
    float4 a0 = sp[0], a1 = sp[1], a2 = sp[2], a3 = sp[3];
    out[(size_t)(b0 + g) * 256 + h] =
        (a0.x + a0.y + a0.z + a0.w) + (a1.x + a1.y + a1.z + a1.w) +
        (a2.x + a2.y + a2.z + a2.w) + (a3.x + a3.y + a3.z + a3.w);
  }
  __syncthreads();

  // ---- layer-2 B-frags (f-invariant): bh[s][g], 64 VGPR ----
  short8 bh[4][G_];
#pragma unroll
  for (int s = 0; s < 4; ++s)
#pragma unroll
    for (int g = 0; g < G_; ++g)
      bh[s][g] = *(const short8*)&hTb[(size_t)(((g * 16 + s * 4 + quad) * 16) + col) * 8];

#pragma unroll
  for (int tt = 0; tt < 2; ++tt)
#pragma unroll
    for (int g = 0; g < G_; ++g) acc2[tt][g] = zf4;

  // ================= layer 2: 39 f, K=128 =================
  for (int f = 0; f < F0; ++f) {
    short8 a[4][2];
#pragma unroll
    for (int s = 0; s < 4; ++s)
#pragma unroll
      for (int tt = 0; tt < 2; ++tt)
        a[s][tt] = wA2[(size_t)((f * 4 + s) * 8 + t0 + tt) * 64 + lane];
    float sx[G_];
#pragma unroll
    for (int g = 0; g < G_; ++g) sx[g] = xs[g][f][col];
#pragma unroll
    for (int tt = 0; tt < 2; ++tt)
#pragma unroll
      for (int g = 0; g < G_; ++g) {
        floatx4 acf = mfma16(a[0][tt], bh[0][g], zf4);
        acf = mfma16(a[1][tt], bh[1][g], acf);
        acf = mfma16(a[2][tt], bh[2][g], acf);
        acf = mfma16(a[3][tt], bh[3][g], acf);
#pragma unroll
        for (int r = 0; r < 4; ++r) acc2[tt][g][r] += acf[r] * sx[g];
      }
  }

  // ---- epilogue 2 ----
#pragma unroll
  for (int tt = 0; tt < 2; ++tt)
#pragma unroll
    for (int g = 0; g < G_; ++g)
#pragma unroll
      for (int r = 0; r < 4; ++r)
        S[(t0 + tt) * 16 + quad * 4 + r][g * 16 + col] = acc2[tt][g][r];
  __syncthreads();
  for (int i = tid; i < G_ * H_; i += 256) {
    int h = i & 127, g = i >> 7;
    const float4* sp = (const float4*)&S[h][g * 16];
    float4 a0 = sp[0], a1 = sp[1], a2 = sp[2], a3 = sp[3];
    out[(size_t)(b0 + g) * 256 + 128 + h] =
        (a0.x + a0.y + a0.z + a0.w) + (a1.x + a1.y + a1.z + a1.w) +
        (a2.x + a2.y + a2.z + a2.w) + (a3.x + a3.y + a3.z + a3.w);
  }
}

// ---------- fp32 fallback (used only if ws too small) ----------
__global__ __launch_bounds__(128) void cin_fused_fallback(const float* __restrict__ x,
                                                          const float* __restrict__ w0,
                                                          const float* __restrict__ w1,
                                                          float* __restrict__ out) {
  __shared__ float4 xs4[F0 * D_ / 4];
  __shared__ float4 h1s4[H_ * D_ / 4];
  __shared__ float4 z4[H_ * D_ / 4];
  const int tid = threadIdx.x;
  const int b = blockIdx.x;
  const int hh = tid >> 2, dd = tid & 3, h0 = hh << 2;
  {
    const float4* xg = (const float4*)(x + (size_t)b * (F0 * D_));
    for (int i = tid; i < F0 * D_ / 4; i += 128) xs4[i] = xg[i];
  }
  __syncthreads();
  float acc[4][4];
#pragma unroll
  for (int i = 0; i < 4; ++i)
#pragma unroll
    for (int j = 0; j < 4; ++j) acc[i][j] = 0.f;
  for (int f = 0; f < F0; ++f) {
    for (int i = tid; i < F0 * D_ / 4; i += 128) {
      float4 xv = xs4[(f << 2) + (i & 3)], qv = xs4[i];
      z4[i] = make_float4(xv.x * qv.x, xv.y * qv.y, xv.z * qv.z, xv.w * qv.w);
    }
    __syncthreads();
    for (int q = 0; q < F0; ++q) {
      float4 zv = z4[(q << 2) + dd];
      int p = f * F0 + q;
      float ww[4] = {w0[(h0 + 0) * P0_ + p], w0[(h0 + 1) * P0_ + p],
                     w0[(h0 + 2) * P0_ + p], w0[(h0 + 3) * P0_ + p]};
      float zz[4] = {zv.x, zv.y, zv.z, zv.w};
#pragma unroll
      for (int hi = 0; hi < 4; ++hi)
#pragma unroll
        for (int di = 0; di < 4; ++di) acc[hi][di] += ww[hi] * zz[di];
    }
    __syncthreads();
  }
#pragma unroll
  for (int hi = 0; hi < 4; ++hi)
    h1s4[(h0 + hi) * 4 + dd] = make_float4(acc[hi][0], acc[hi][1], acc[hi][2], acc[hi][3]);
  __syncthreads();
  {
    float4 a0 = h1s4[tid * 4 + 0], a1 = h1s4[tid * 4 + 1];
    float4 a2 = h1s4[tid * 4 + 2], a3 = h1s4[tid * 4 + 3];
    out[(size_t)b * 256 + tid] = (a0.x + a0.y + a0.z + a0.w) + (a1.x + a1.y + a1.z + a1.w) +
                                 (a2.x + a2.y + a2.z + a2.w) + (a3.x + a3.y + a3.z + a3.w);
  }
#pragma unroll
  for (int i = 0; i < 4; ++i)
#pragma unroll
    for (int j = 0; j < 4; ++j) acc[i][j] = 0.f;
  for (int f = 0; f < F0; ++f) {
    for (int i = tid; i < H_ * D_ / 4; i += 128) {
      float4 xv = xs4[(f << 2) + (i & 3)], hv = h1s4[i];
      z4[i] = make_float4(xv.x * hv.x, xv.y * hv.y, xv.z * hv.z, xv.w * hv.w);
    }
    __syncthreads();
    for (int q = 0; q < H_; ++q) {
      float4 zv = z4[(q << 2) + dd];
      int p = f * H_ + q;
      float ww[4] = {w1[(h0 + 0) * P1_ + p], w1[(h0 + 1) * P1_ + p],
                     w1[(h0 + 2) * P1_ + p], w1[(h0 + 3) * P1_ + p]};
      float zz[4] = {zv.x, zv.y, zv.z, zv.w};
#pragma unroll
      for (int hi = 0; hi < 4; ++hi)
#pragma unroll
        for (int di = 0; di < 4; ++di) acc[hi][di] += ww[hi] * zz[di];
    }
    __syncthreads();
  }
#pragma unroll
  for (int hi = 0; hi < 4; ++hi)
    z4[(h0 + hi) * 4 + dd] = make_float4(acc[hi][0], acc[hi][1], acc[hi][2], acc[hi][3]);
  __syncthreads();
  {
    float4 a0 = z4[tid * 4 + 0], a1 = z4[tid * 4 + 1];
    float4 a2 = z4[tid * 4 + 2], a3 = z4[tid * 4 + 3];
    out[(size_t)b * 256 + 128 + tid] = (a0.x + a0.y + a0.z + a0.w) + (a1.x + a1.y + a1.z + a1.w) +
                                       (a2.x + a2.y + a2.z + a2.w) + (a3.x + a3.y + a3.z + a3.w);
  }
}

extern "C" void kernel_launch(void* const* d_in, const int* in_sizes, int n_in,
                              void* d_out, int out_size, void* d_ws, size_t ws_size,
                              hipStream_t stream) {
  const float* x  = (const float*)d_in[0];
  const float* w0 = (const float*)d_in[1];
  const float* w1 = (const float*)d_in[2];
  float* out = (float*)d_out;

  const size_t need = (size_t)(NF1 + NF2) * 64 * sizeof(short8);  // ~1.92 MB
  if (ws_size >= need) {
    short8* wA1 = (short8*)d_ws;
    short8* wA2 = wA1 + (size_t)NF1 * 64;
    const int nthr = (NF1 + NF2) * 64;           // 119808
    pack_w_kernel<<<(nthr + 255) / 256, 256, 0, stream>>>(w0, w1, wA1, wA2);
    cin_mfma_kernel<<<NBLK, 256, 0, stream>>>(x, wA1, wA2, out);
  } else {
    cin_fused_fallback<<<2048, 128, 0, stream>>>(x, w0, w1, out);
  }
}